// Round 1
// baseline (297.925 us; speedup 1.0000x reference)
//
#include <hip/hip_runtime.h>

// Problem constants (from reference): B=128, NU=NI=5000, E=128, UF=IF=16, D=288
#define PB 128
#define PNU 5000
#define PE 128
#define PUF 16
#define PD 288            // 2*E + UF + IF
#define PG3 384           // 3*E

constexpr long MEM_ELEMS = (long)PB * PNU * PE;   // 81,920,000 floats per memory
constexpr int  OUT_HEAD  = PB * 2 * PE;           // 32,768 floats (out tensor)

// ---------------------------------------------------------------------------
// Kernel 1: bulk copy user_memory / item_memory into their d_out slots.
// Pure bandwidth: float4 grid-stride copy. This is ~1.31 GB of HBM traffic
// and dominates total time; everything else is noise.
// ---------------------------------------------------------------------------
__global__ __launch_bounds__(256) void copy_mem_kernel(
    const float4* __restrict__ um, const float4* __restrict__ im,
    float4* __restrict__ oum, float4* __restrict__ oim, long n4) {
  long i = (long)blockIdx.x * blockDim.x + threadIdx.x;
  long stride = (long)gridDim.x * blockDim.x;
  for (; i < n4; i += stride) {
    oum[i] = um[i];
    oim[i] = im[i];
  }
}

// ---------------------------------------------------------------------------
// Kernel 2: fused gather -> GRUCell(h=0) -> L2-normalize -> scatter + out.
// One 128-thread block per (batch, side). side 0 = user, side 1 = item.
// Thread t owns output element t: computes rows t, E+t, 2E+t of W @ x.
// Runs after the copy on the same stream, so its scatter overwrites the
// copied rows (ordering is guaranteed by stream serialization).
// ---------------------------------------------------------------------------
__global__ __launch_bounds__(128) void gru_kernel(
    const int* __restrict__ user_ids, const int* __restrict__ item_ids,
    const float* __restrict__ user_feat, const float* __restrict__ item_feat,
    const float* __restrict__ um_in, const float* __restrict__ im_in,
    const float* __restrict__ Wu, const float* __restrict__ bihu, const float* __restrict__ bhhu,
    const float* __restrict__ Wi, const float* __restrict__ bihi, const float* __restrict__ bhhi,
    float* __restrict__ out, float* __restrict__ um_out, float* __restrict__ im_out) {
  const int b = blockIdx.x;
  const int side = blockIdx.y;  // 0 = user update, 1 = item update
  const int t = threadIdx.x;    // 0..127

  __shared__ float x[PD];
  __shared__ float wsum[2];

  const int uid = user_ids[b];
  const int iid = item_ids[b];
  const float* umrow = um_in + ((long)b * PNU + uid) * PE;
  const float* imrow = im_in + ((long)b * PNU + iid) * PE;

  // Build the concatenated input vector in LDS.
  // side 0: [um(128), user_feat(16), im(128), item_feat(16)]
  // side 1: [im(128), item_feat(16), um(128), user_feat(16)]
  if (side == 0) {
    x[t] = umrow[t];
    x[PE + PUF + t] = imrow[t];
    if (t < PUF) {
      x[PE + t]           = user_feat[b * PUF + t];
      x[2 * PE + PUF + t] = item_feat[b * PUF + t];
    }
  } else {
    x[t] = imrow[t];
    x[PE + PUF + t] = umrow[t];
    if (t < PUF) {
      x[PE + t]           = item_feat[b * PUF + t];
      x[2 * PE + PUF + t] = user_feat[b * PUF + t];
    }
  }
  __syncthreads();

  const float* W   = side ? Wi   : Wu;
  const float* bih = side ? bihi : bihu;
  const float* bhh = side ? bhhi : bhhu;

  // Rows are 288 floats = 1152 B, 16B-aligned -> float4 loads are valid.
  const float4* x4  = reinterpret_cast<const float4*>(x);
  const float4* wr4 = reinterpret_cast<const float4*>(W + (long)t * PD);
  const float4* wz4 = reinterpret_cast<const float4*>(W + (long)(PE + t) * PD);
  const float4* wn4 = reinterpret_cast<const float4*>(W + (long)(2 * PE + t) * PD);

  float ar = 0.f, az = 0.f, an = 0.f;
#pragma unroll 8
  for (int k = 0; k < PD / 4; ++k) {
    const float4 xv = x4[k];  // LDS broadcast (same addr across lanes)
    const float4 a = wr4[k];
    ar += a.x * xv.x + a.y * xv.y + a.z * xv.z + a.w * xv.w;
    const float4 c = wz4[k];
    az += c.x * xv.x + c.y * xv.y + c.z * xv.z + c.w * xv.w;
    const float4 e = wn4[k];
    an += e.x * xv.x + e.y * xv.y + e.z * xv.z + e.w * xv.w;
  }

  // GRUCell with h = 0 (gate order r, z, n):
  const float r = 1.f / (1.f + expf(-(ar + bih[t] + bhh[t])));
  const float z = 1.f / (1.f + expf(-(az + bih[PE + t] + bhh[PE + t])));
  const float n = tanhf(an + bih[2 * PE + t] + r * bhh[2 * PE + t]);
  const float h = (1.f - z) * n;

  // L2 norm over the 128 outputs: wave-64 shuffle reduce + LDS combine.
  float s = h * h;
  for (int off = 32; off; off >>= 1) s += __shfl_down(s, off, 64);
  if ((t & 63) == 0) wsum[t >> 6] = s;
  __syncthreads();
  const float inv = 1.f / fmaxf(sqrtf(wsum[0] + wsum[1]), 1e-12f);
  const float hn = h * inv;

  // out[b] = concat(u_new, i_new)
  out[(long)b * (2 * PE) + side * PE + t] = hn;

  // scatter into the copied memories in d_out
  if (side == 0) um_out[((long)b * PNU + uid) * PE + t] = hn;
  else           im_out[((long)b * PNU + iid) * PE + t] = hn;
}

extern "C" void kernel_launch(void* const* d_in, const int* in_sizes, int n_in,
                              void* d_out, int out_size, void* d_ws, size_t ws_size,
                              hipStream_t stream) {
  const int*   user_ids  = (const int*)d_in[0];
  const int*   item_ids  = (const int*)d_in[1];
  const float* user_feat = (const float*)d_in[2];
  const float* item_feat = (const float*)d_in[3];
  const float* um        = (const float*)d_in[4];
  const float* im        = (const float*)d_in[5];
  const float* Wu        = (const float*)d_in[6];
  const float* bihu      = (const float*)d_in[7];
  const float* bhhu      = (const float*)d_in[8];
  const float* Wi        = (const float*)d_in[9];
  const float* bihi      = (const float*)d_in[10];
  const float* bhhi      = (const float*)d_in[11];

  float* out    = (float*)d_out;
  float* um_out = out + OUT_HEAD;          // 16B-aligned (32768*4 bytes)
  float* im_out = um_out + MEM_ELEMS;      // 16B-aligned

  const long n4 = MEM_ELEMS / 4;           // 20,480,000 float4 per memory
  copy_mem_kernel<<<2048, 256, 0, stream>>>(
      (const float4*)um, (const float4*)im, (float4*)um_out, (float4*)im_out, n4);

  dim3 grid(PB, 2);
  gru_kernel<<<grid, 128, 0, stream>>>(
      user_ids, item_ids, user_feat, item_feat, um, im,
      Wu, bihu, bhhu, Wi, bihi, bhhi, out, um_out, im_out);
}

// Round 2
// 269.740 us; speedup vs baseline: 1.1045x; 1.1045x over previous
//
#include <hip/hip_runtime.h>

// Problem constants (from reference): B=128, NU=NI=5000, E=128, UF=IF=16, D=288
#define PB 128
#define PNU 5000
#define PE 128
#define PUF 16
#define PD 288            // 2*E + UF + IF

constexpr long MEM_ELEMS = (long)PB * PNU * PE;   // 81,920,000 floats per memory
constexpr int  OUT_HEAD  = PB * 2 * PE;           // 32,768 floats (out tensor)

typedef float f32x4 __attribute__((ext_vector_type(4)));

// ---------------------------------------------------------------------------
// Kernel 1: bulk copy user_memory / item_memory into their d_out slots.
// 2.6 GB total streaming traffic >> 256 MB L3 -> nontemporal loads/stores to
// bypass cache allocation. float4 grid-stride, 4096 blocks for deep MLP.
// ---------------------------------------------------------------------------
__global__ __launch_bounds__(256) void copy_mem_kernel(
    const f32x4* __restrict__ um, const f32x4* __restrict__ im,
    f32x4* __restrict__ oum, f32x4* __restrict__ oim, long n4) {
  long i = (long)blockIdx.x * blockDim.x + threadIdx.x;
  const long stride = (long)gridDim.x * blockDim.x;
  for (; i < n4; i += stride) {
    f32x4 a = __builtin_nontemporal_load(&um[i]);
    f32x4 b = __builtin_nontemporal_load(&im[i]);
    __builtin_nontemporal_store(a, &oum[i]);
    __builtin_nontemporal_store(b, &oim[i]);
  }
}

// ---------------------------------------------------------------------------
// Kernel 2: fused gather -> GRUCell(h=0) -> L2-normalize -> scatter + out.
// One 128-thread block per (batch, side). side 0 = user, side 1 = item.
// Runs after the copy on the same stream, so its scatter overwrites the
// copied rows (stream ordering guarantees this).
// ---------------------------------------------------------------------------
__global__ __launch_bounds__(128) void gru_kernel(
    const int* __restrict__ user_ids, const int* __restrict__ item_ids,
    const float* __restrict__ user_feat, const float* __restrict__ item_feat,
    const float* __restrict__ um_in, const float* __restrict__ im_in,
    const float* __restrict__ Wu, const float* __restrict__ bihu, const float* __restrict__ bhhu,
    const float* __restrict__ Wi, const float* __restrict__ bihi, const float* __restrict__ bhhi,
    float* __restrict__ out, float* __restrict__ um_out, float* __restrict__ im_out) {
  const int b = blockIdx.x;
  const int side = blockIdx.y;  // 0 = user update, 1 = item update
  const int t = threadIdx.x;    // 0..127

  __shared__ float x[PD];
  __shared__ float wsum[2];

  const int uid = user_ids[b];
  const int iid = item_ids[b];
  const float* umrow = um_in + ((long)b * PNU + uid) * PE;
  const float* imrow = im_in + ((long)b * PNU + iid) * PE;

  // Build the concatenated input vector in LDS.
  // side 0: [um(128), user_feat(16), im(128), item_feat(16)]
  // side 1: [im(128), item_feat(16), um(128), user_feat(16)]
  if (side == 0) {
    x[t] = umrow[t];
    x[PE + PUF + t] = imrow[t];
    if (t < PUF) {
      x[PE + t]           = user_feat[b * PUF + t];
      x[2 * PE + PUF + t] = item_feat[b * PUF + t];
    }
  } else {
    x[t] = imrow[t];
    x[PE + PUF + t] = umrow[t];
    if (t < PUF) {
      x[PE + t]           = item_feat[b * PUF + t];
      x[2 * PE + PUF + t] = user_feat[b * PUF + t];
    }
  }
  __syncthreads();

  const float* W   = side ? Wi   : Wu;
  const float* bih = side ? bihi : bihu;
  const float* bhh = side ? bhhi : bhhu;

  // Rows are 288 floats = 1152 B, 16B-aligned -> float4 loads are valid.
  const float4* x4  = reinterpret_cast<const float4*>(x);
  const float4* wr4 = reinterpret_cast<const float4*>(W + (long)t * PD);
  const float4* wz4 = reinterpret_cast<const float4*>(W + (long)(PE + t) * PD);
  const float4* wn4 = reinterpret_cast<const float4*>(W + (long)(2 * PE + t) * PD);

  float ar = 0.f, az = 0.f, an = 0.f;
#pragma unroll 8
  for (int k = 0; k < PD / 4; ++k) {
    const float4 xv = x4[k];  // LDS broadcast (same addr across lanes)
    const float4 a = wr4[k];
    ar += a.x * xv.x + a.y * xv.y + a.z * xv.z + a.w * xv.w;
    const float4 c = wz4[k];
    az += c.x * xv.x + c.y * xv.y + c.z * xv.z + c.w * xv.w;
    const float4 e = wn4[k];
    an += e.x * xv.x + e.y * xv.y + e.z * xv.z + e.w * xv.w;
  }

  // GRUCell with h = 0 (gate order r, z, n):
  const float r = 1.f / (1.f + expf(-(ar + bih[t] + bhh[t])));
  const float z = 1.f / (1.f + expf(-(az + bih[PE + t] + bhh[PE + t])));
  const float n = tanhf(an + bih[2 * PE + t] + r * bhh[2 * PE + t]);
  const float h = (1.f - z) * n;

  // L2 norm over the 128 outputs: wave-64 shuffle reduce + LDS combine.
  float s = h * h;
  for (int off = 32; off; off >>= 1) s += __shfl_down(s, off, 64);
  if ((t & 63) == 0) wsum[t >> 6] = s;
  __syncthreads();
  const float inv = 1.f / fmaxf(sqrtf(wsum[0] + wsum[1]), 1e-12f);
  const float hn = h * inv;

  // out[b] = concat(u_new, i_new)
  out[(long)b * (2 * PE) + side * PE + t] = hn;

  // scatter into the copied memories in d_out
  if (side == 0) um_out[((long)b * PNU + uid) * PE + t] = hn;
  else           im_out[((long)b * PNU + iid) * PE + t] = hn;
}

extern "C" void kernel_launch(void* const* d_in, const int* in_sizes, int n_in,
                              void* d_out, int out_size, void* d_ws, size_t ws_size,
                              hipStream_t stream) {
  const int*   user_ids  = (const int*)d_in[0];
  const int*   item_ids  = (const int*)d_in[1];
  const float* user_feat = (const float*)d_in[2];
  const float* item_feat = (const float*)d_in[3];
  const float* um        = (const float*)d_in[4];
  const float* im        = (const float*)d_in[5];
  const float* Wu        = (const float*)d_in[6];
  const float* bihu      = (const float*)d_in[7];
  const float* bhhu      = (const float*)d_in[8];
  const float* Wi        = (const float*)d_in[9];
  const float* bihi      = (const float*)d_in[10];
  const float* bhhi      = (const float*)d_in[11];

  float* out    = (float*)d_out;
  float* um_out = out + OUT_HEAD;          // 16B-aligned (32768*4 bytes)
  float* im_out = um_out + MEM_ELEMS;      // 16B-aligned

  const long n4 = MEM_ELEMS / 4;           // 20,480,000 float4 per memory
  copy_mem_kernel<<<4096, 256, 0, stream>>>(
      (const f32x4*)um, (const f32x4*)im, (f32x4*)um_out, (f32x4*)im_out, n4);

  dim3 grid(PB, 2);
  gru_kernel<<<grid, 128, 0, stream>>>(
      user_ids, item_ids, user_feat, item_feat, um, im,
      Wu, bihu, bhhu, Wi, bihi, bhhi, out, um_out, im_out);
}